// Round 5
// baseline (247.655 us; speedup 1.0000x reference)
//
#include <hip/hip_runtime.h>

// CharacteristicLineEncoder: B=4096, DIM=3, L=300, S=60, P=5, E=128
// out[b,s,e] = sum_p W_lr[s,p]*relu(W_le[e,:]·x[b,:,5s+p] + b_le[e]) + b_lr[s]
//            + relu( sum_l W_gn[l]*relu(W_ge[e,:]·x[b,:,l] + b_ge[e]) + b_gn )
//
// 384 threads = 3 balanced L-thirds x 128 e-lanes. Third q owns regions
// s = 20q..20q+19 (100 l = 25 quads), 5 groups of 4 regions -> la[20]
// (statically indexed) + 4 global accs ~= 60 VGPR -> no spill, 8 waves/SIMD.
// x staged in LDS (broadcast ds_read_b128); l-indexed weights on the scalar
// path; global-branch partials combined across thirds via LDS.

#define Bv 4096
#define Sv 60
#define Ev 128

#define RELU(v) fmaxf((v), 0.0f)

__global__ __launch_bounds__(384, 6) void cle_kernel(
    const float* __restrict__ x,     // [B,3,300]
    const float* __restrict__ W_le,  // [E,3]
    const float* __restrict__ b_le,  // [E]
    const float* __restrict__ W_lr,  // [300]
    const float* __restrict__ b_lr,  // [S]
    const float* __restrict__ W_ge,  // [E,3]
    const float* __restrict__ b_ge,  // [E]
    const float* __restrict__ W_gn,  // [300]
    const float* __restrict__ b_gn,  // [1]
    float* __restrict__ out)         // [B,S,E]
{
    const int tid = threadIdx.x;
    const int e = tid & 127;     // embedding channel
    const int q = tid >> 7;      // L-third 0..2 (wave-uniform)
    const int b = blockIdx.x;

    __shared__ __align__(16) float4 sx4[225];  // x[b]: channel c quad j at [c*75+j]
    __shared__ float sg[384];                  // global-branch partials

    {
        const float4* xg4 = (const float4*)(x + (size_t)b * 900);
        if (tid < 225) sx4[tid] = xg4[tid];
    }

    const float wl0 = W_le[e * 3 + 0], wl1 = W_le[e * 3 + 1], wl2 = W_le[e * 3 + 2];
    const float bl  = b_le[e];
    const float wg0 = W_ge[e * 3 + 0], wg1 = W_ge[e * 3 + 1], wg2 = W_ge[e * 3 + 2];
    const float bg  = b_ge[e];
    const float bgn = b_gn[0];

    __syncthreads();

    const int qb = q * 25;   // quad base for this third (l base = 100q)

    float g0 = 0.f, g1 = 0.f, g2 = 0.f, g3 = 0.f;
    float la[20];
#pragma unroll
    for (int i = 0; i < 20; ++i) la[i] = 0.0f;

#define GEq(cmp) RELU(fmaf(wg2, c2.cmp, fmaf(wg1, c1.cmp, fmaf(wg0, c0.cmp, bg))))
#define LEq(cmp) RELU(fmaf(wl2, c2.cmp, fmaf(wl1, c1.cmp, fmaf(wl0, c0.cmp, bl))))
#define DOQ(qi, A0, A1, A2, A3)                                            \
    {                                                                      \
        const int qq = q0 + (qi);                                          \
        const int l4 = qq * 4;                                             \
        const float4 c0 = sx4[qq], c1 = sx4[75 + qq], c2 = sx4[150 + qq];  \
        g0 = fmaf(W_gn[l4 + 0], GEq(x), g0);                               \
        g1 = fmaf(W_gn[l4 + 1], GEq(y), g1);                               \
        g2 = fmaf(W_gn[l4 + 2], GEq(z), g2);                               \
        g3 = fmaf(W_gn[l4 + 3], GEq(w), g3);                               \
        A0 = fmaf(W_lr[l4 + 0], LEq(x), A0);                               \
        A1 = fmaf(W_lr[l4 + 1], LEq(y), A1);                               \
        A2 = fmaf(W_lr[l4 + 2], LEq(z), A2);                               \
        A3 = fmaf(W_lr[l4 + 3], LEq(w), A3);                               \
    }

    // 5 groups of 4 regions each (group = 20 l = 5 quads), all thirds balanced
#pragma unroll
    for (int g = 0; g < 5; ++g) {
        const int q0 = qb + g * 5;
        const int r = g << 2;
        // element t = 4*qi + component (l = 100q + 20g + t), region += t/5
        DOQ(0, la[r + 0], la[r + 0], la[r + 0], la[r + 0])  // t 0..3
        DOQ(1, la[r + 0], la[r + 1], la[r + 1], la[r + 1])  // t 4..7
        DOQ(2, la[r + 1], la[r + 1], la[r + 2], la[r + 2])  // t 8..11
        DOQ(3, la[r + 2], la[r + 2], la[r + 2], la[r + 3])  // t 12..15
        DOQ(4, la[r + 3], la[r + 3], la[r + 3], la[r + 3])  // t 16..19
    }

    // combine global-branch partials across the 3 thirds
    sg[tid] = (g0 + g1) + (g2 + g3);
    __syncthreads();
    const float gf = RELU((sg[e] + sg[128 + e]) + sg[256 + e] + bgn);

    // stores: third q writes s = 20q + 4g + j
    float* ob = out + (size_t)b * (Sv * Ev) + (size_t)(q * 20) * Ev + e;
#pragma unroll
    for (int g = 0; g < 5; ++g) {
        const int r = g << 2;
        const int s0 = q * 20 + (g << 2);
        float* og = ob + (size_t)(g << 2) * Ev;
        og[0 * Ev] = (la[r + 0] + gf) + b_lr[s0 + 0];
        og[1 * Ev] = (la[r + 1] + gf) + b_lr[s0 + 1];
        og[2 * Ev] = (la[r + 2] + gf) + b_lr[s0 + 2];
        og[3 * Ev] = (la[r + 3] + gf) + b_lr[s0 + 3];
    }
}

extern "C" void kernel_launch(void* const* d_in, const int* in_sizes, int n_in,
                              void* d_out, int out_size, void* d_ws, size_t ws_size,
                              hipStream_t stream) {
    const float* x    = (const float*)d_in[0];
    const float* W_le = (const float*)d_in[1];
    const float* b_le = (const float*)d_in[2];
    const float* W_lr = (const float*)d_in[3];
    const float* b_lr = (const float*)d_in[4];
    const float* W_ge = (const float*)d_in[5];
    const float* b_ge = (const float*)d_in[6];
    const float* W_gn = (const float*)d_in[7];
    const float* b_gn = (const float*)d_in[8];
    float* out = (float*)d_out;

    cle_kernel<<<Bv, 384, 0, stream>>>(x, W_le, b_le, W_lr, b_lr,
                                       W_ge, b_ge, W_gn, b_gn, out);
}

// Round 6
// 79.363 us; speedup vs baseline: 3.1206x; 3.1206x over previous
//
#include <hip/hip_runtime.h>

// CharacteristicLineEncoder: B=4096, DIM=3, L=300, S=60, P=5, E=128
// out[b,s,e] = sum_p W_lr[s,p]*relu(W_le[e,:]·x[b,:,5s+p] + b_le[e]) + b_lr[s]
//            + relu( sum_l W_gn[l]*relu(W_ge[e,:]·x[b,:,l] + b_ge[e]) + b_gn )
//
// 384 threads = 3 balanced L-thirds x 128 e-lanes. Third q owns regions
// s = 20q..20q+19 (100 l = 25 quads): la[20] + 4 global accs, statically
// indexed, fully unrolled. Fused single sweep: x broadcast from LDS
// (225 ds_read_b128/wave, the minimum), l-indexed weights on the scalar
// path. NOTE: plain __launch_bounds__(384) — the min-waves variant made
// the allocator spill la[] to scratch in R4/R5 (VGPR 32/40, +670MB HBM).

#define Bv 4096
#define Sv 60
#define Ev 128

#define RELU(v) fmaxf((v), 0.0f)

__global__ __launch_bounds__(384) void cle_kernel(
    const float* __restrict__ x,     // [B,3,300]
    const float* __restrict__ W_le,  // [E,3]
    const float* __restrict__ b_le,  // [E]
    const float* __restrict__ W_lr,  // [300]
    const float* __restrict__ b_lr,  // [S]
    const float* __restrict__ W_ge,  // [E,3]
    const float* __restrict__ b_ge,  // [E]
    const float* __restrict__ W_gn,  // [300]
    const float* __restrict__ b_gn,  // [1]
    float* __restrict__ out)         // [B,S,E]
{
    const int tid = threadIdx.x;
    const int e = tid & 127;     // embedding channel
    const int q = tid >> 7;      // L-third 0..2 (wave-uniform)
    const int b = blockIdx.x;

    __shared__ __align__(16) float4 sx4[225];  // x[b]: channel c quad j at [c*75+j]
    __shared__ float sg[384];                  // global-branch partials

    {
        const float4* xg4 = (const float4*)(x + (size_t)b * 900);
        if (tid < 225) sx4[tid] = xg4[tid];
    }

    const float wl0 = W_le[e * 3 + 0], wl1 = W_le[e * 3 + 1], wl2 = W_le[e * 3 + 2];
    const float bl  = b_le[e];
    const float wg0 = W_ge[e * 3 + 0], wg1 = W_ge[e * 3 + 1], wg2 = W_ge[e * 3 + 2];
    const float bg  = b_ge[e];
    const float bgn = b_gn[0];

    __syncthreads();

    const int qb = q * 25;   // quad base for this third (l base = 100q)

    float g0 = 0.f, g1 = 0.f, g2 = 0.f, g3 = 0.f;
    float la[20];
#pragma unroll
    for (int i = 0; i < 20; ++i) la[i] = 0.0f;

#define GEq(cmp) RELU(fmaf(wg2, c2.cmp, fmaf(wg1, c1.cmp, fmaf(wg0, c0.cmp, bg))))
#define LEq(cmp) RELU(fmaf(wl2, c2.cmp, fmaf(wl1, c1.cmp, fmaf(wl0, c0.cmp, bl))))
#define DOQ(qi, A0, A1, A2, A3)                                            \
    {                                                                      \
        const int qq = q0 + (qi);                                          \
        const int l4 = qq * 4;                                             \
        const float4 c0 = sx4[qq], c1 = sx4[75 + qq], c2 = sx4[150 + qq];  \
        g0 = fmaf(W_gn[l4 + 0], GEq(x), g0);                               \
        g1 = fmaf(W_gn[l4 + 1], GEq(y), g1);                               \
        g2 = fmaf(W_gn[l4 + 2], GEq(z), g2);                               \
        g3 = fmaf(W_gn[l4 + 3], GEq(w), g3);                               \
        A0 = fmaf(W_lr[l4 + 0], LEq(x), A0);                               \
        A1 = fmaf(W_lr[l4 + 1], LEq(y), A1);                               \
        A2 = fmaf(W_lr[l4 + 2], LEq(z), A2);                               \
        A3 = fmaf(W_lr[l4 + 3], LEq(w), A3);                               \
    }

    // 5 groups of 4 regions each (group = 20 l = 5 quads), all thirds balanced
#pragma unroll
    for (int g = 0; g < 5; ++g) {
        const int q0 = qb + g * 5;
        const int r = g << 2;
        // element t = 4*qi + component (l = 100q + 20g + t), region += t/5
        DOQ(0, la[r + 0], la[r + 0], la[r + 0], la[r + 0])  // t 0..3
        DOQ(1, la[r + 0], la[r + 1], la[r + 1], la[r + 1])  // t 4..7
        DOQ(2, la[r + 1], la[r + 1], la[r + 2], la[r + 2])  // t 8..11
        DOQ(3, la[r + 2], la[r + 2], la[r + 2], la[r + 3])  // t 12..15
        DOQ(4, la[r + 3], la[r + 3], la[r + 3], la[r + 3])  // t 16..19
    }

    // combine global-branch partials across the 3 thirds
    sg[tid] = (g0 + g1) + (g2 + g3);
    __syncthreads();
    const float gf = RELU((sg[e] + sg[128 + e]) + sg[256 + e] + bgn);

    // stores: third q writes s = 20q + 4g + j
    float* ob = out + (size_t)b * (Sv * Ev) + (size_t)(q * 20) * Ev + e;
#pragma unroll
    for (int g = 0; g < 5; ++g) {
        const int r = g << 2;
        const int s0 = q * 20 + (g << 2);
        float* og = ob + (size_t)(g << 2) * Ev;
        og[0 * Ev] = (la[r + 0] + gf) + b_lr[s0 + 0];
        og[1 * Ev] = (la[r + 1] + gf) + b_lr[s0 + 1];
        og[2 * Ev] = (la[r + 2] + gf) + b_lr[s0 + 2];
        og[3 * Ev] = (la[r + 3] + gf) + b_lr[s0 + 3];
    }
}

extern "C" void kernel_launch(void* const* d_in, const int* in_sizes, int n_in,
                              void* d_out, int out_size, void* d_ws, size_t ws_size,
                              hipStream_t stream) {
    const float* x    = (const float*)d_in[0];
    const float* W_le = (const float*)d_in[1];
    const float* b_le = (const float*)d_in[2];
    const float* W_lr = (const float*)d_in[3];
    const float* b_lr = (const float*)d_in[4];
    const float* W_ge = (const float*)d_in[5];
    const float* b_ge = (const float*)d_in[6];
    const float* W_gn = (const float*)d_in[7];
    const float* b_gn = (const float*)d_in[8];
    float* out = (float*)d_out;

    cle_kernel<<<Bv, 384, 0, stream>>>(x, W_le, b_le, W_lr, b_lr,
                                       W_ge, b_ge, W_gn, b_gn, out);
}